// Round 6
// baseline (37.839 us; speedup 1.0000x reference)
//
#include <hip/hip_runtime.h>
#include <math.h>

#define BLOCK 256
#define TAPS 16
#define HALO (TAPS - 1)
#define EPW 64            // elements per wave
#define F4_PER_ELEM 32    // 128 floats per element

__device__ __forceinline__ float eluf(float v) { return v > 0.0f ? v : expm1f(v); }

__device__ __forceinline__ float dot4(float4 a, float4 b) {
    return a.x * b.x + a.y * b.y + a.z * b.z + a.w * b.w;
}

// Halo path: direct (scattered) global reads — used by only 15 threads/block.
__device__ __forceinline__ void compute_s_global(const float4* __restrict__ xp,
        const float4* __restrict__ w1v, float bias1,
        const float* __restrict__ w2, float b20, float b21,
        float& sr, float& si) {
    float h[4];
#pragma unroll
    for (int j = 0; j < 4; ++j) {
        float acc = bias1;
#pragma unroll
        for (int c = 0; c < 2; ++c)
#pragma unroll
            for (int q = 0; q < 4; ++q)
                acc += dot4(xp[c * 16 + j * 4 + q], w1v[c * 4 + q]);
        h[j] = eluf(acc);
    }
    float a0 = b20, a1 = b21;
#pragma unroll
    for (int j = 0; j < 4; ++j) { a0 += h[j] * w2[j]; a1 += h[j] * w2[4 + j]; }
    sr = eluf(a0);
    si = eluf(a1);
}

// Main path: element data staged in LDS, xor-swizzled at float4 granularity.
__device__ __forceinline__ void compute_s_lds(const float4* row, int key,
        const float4* __restrict__ w1v, float bias1,
        const float* __restrict__ w2, float b20, float b21,
        float& sr, float& si) {
    float h[4];
#pragma unroll
    for (int j = 0; j < 4; ++j) {
        float acc = bias1;
#pragma unroll
        for (int c = 0; c < 2; ++c)
#pragma unroll
            for (int q = 0; q < 4; ++q)
                acc += dot4(row[(c * 16 + j * 4 + q) ^ key], w1v[c * 4 + q]);
        h[j] = eluf(acc);
    }
    float a0 = b20, a1 = b21;
#pragma unroll
    for (int j = 0; j < 4; ++j) { a0 += h[j] * w2[j]; a1 += h[j] * w2[4 + j]; }
    sr = eluf(a0);
    si = eluf(a1);
}

__global__ __launch_bounds__(BLOCK) void NF_20581483282566_kernel(
    const float* __restrict__ x,
    const float* __restrict__ w1, const float* __restrict__ b1,
    const float* __restrict__ w2, const float* __restrict__ b2,
    const float* __restrict__ tr, const float* __restrict__ ti,
    float* __restrict__ out, int B)
{
    __shared__ float4 xs[4 * EPW * F4_PER_ELEM];   // 128 KiB staging tile
    __shared__ float s_r[BLOCK + HALO];
    __shared__ float s_i[BLOCK + HALO];

    const int t = threadIdx.x;
    const int w = t >> 6;        // wave id (0..3)
    const int l = t & 63;        // lane id
    const long b0 = (long)blockIdx.x * BLOCK;
    const long b  = b0 + t;
    const long ebase = b0 + (long)w * EPW;   // first element owned by this wave

    const float4* xf4 = reinterpret_cast<const float4*>(x);
    const float4* w1v = reinterpret_cast<const float4*>(w1);
    const float bias1 = b1[0];
    const float b20 = b2[0], b21 = b2[1];

    float4* wlds = xs + w * (EPW * F4_PER_ELEM);

    // ---- coalesced staging: global (linear) -> regs -> LDS (swizzled) ----
    // wave region linear f4 position p = k*64 + l maps to local element
    // bl = p>>5, within-element f4 i = p&31 = l&31; LDS dst = bl*32 + (i ^ (bl&7)).
    float4 tmp[32];
    const bool full = (b0 + BLOCK) <= (long)B;
    if (full) {
#pragma unroll
        for (int k = 0; k < 32; ++k)
            tmp[k] = xf4[ebase * 32 + (long)(k * 64 + l)];
    } else {
#pragma unroll
        for (int k = 0; k < 32; ++k) {
            int bl = 2 * k + (l >> 5);
            if (ebase + bl < (long)B)
                tmp[k] = xf4[ebase * 32 + (long)(k * 64 + l)];
            else
                tmp[k] = make_float4(0.f, 0.f, 0.f, 0.f);
        }
    }
#pragma unroll
    for (int k = 0; k < 32; ++k) {
        int bl = 2 * k + (l >> 5);
        int dst = bl * 32 + ((l & 31) ^ (bl & 7));
        wlds[dst] = tmp[k];
    }

    // ---- halo: previous block's last 15 s-values, recomputed directly ----
    if (t < HALO) {
        long hb = b0 - HALO + t;
        float hr = 0.f, hi = 0.f;
        if (hb >= 0)
            compute_s_global(xf4 + hb * 32, w1v, bias1, w2, b20, b21, hr, hi);
        s_r[t] = hr;
        s_i[t] = hi;
    }
    __syncthreads();

    // ---- per-element conv1+conv2 from LDS (bank-group balanced reads) ----
    float sr = 0.f, si = 0.f;
    if (b < (long)B)
        compute_s_lds(wlds + l * F4_PER_ELEM, l & 7, w1v, bias1, w2, b20, b21, sr, si);
    s_r[HALO + t] = sr;
    s_i[HALO + t] = si;
    __syncthreads();

    // ---- 16-tap complex FIR along batch axis ----
    if (b < (long)B) {
        float yr = 0.f, yi = 0.f;
#pragma unroll
        for (int j = 0; j < TAPS; ++j) {
            float a = s_r[HALO + t - j];
            float c = s_i[HALO + t - j];
            float trj = tr[j], tij = ti[j];
            yr += a * trj - c * tij;
            yi += a * tij + c * trj;
        }
        reinterpret_cast<float2*>(out)[b] = make_float2(yr, yi);
    }
}

extern "C" void kernel_launch(void* const* d_in, const int* in_sizes, int n_in,
                              void* d_out, int out_size, void* d_ws, size_t ws_size,
                              hipStream_t stream) {
    const float* x  = (const float*)d_in[0];
    const float* w1 = (const float*)d_in[1];
    const float* b1 = (const float*)d_in[2];
    const float* w2 = (const float*)d_in[3];
    const float* b2 = (const float*)d_in[4];
    const float* tr = (const float*)d_in[5];
    const float* ti = (const float*)d_in[6];
    float* out = (float*)d_out;

    const int B = in_sizes[0] / 128;  // x is (B, 2, 64)
    const int grid = (B + BLOCK - 1) / BLOCK;
    NF_20581483282566_kernel<<<grid, BLOCK, 0, stream>>>(x, w1, b1, w2, b2, tr, ti, out, B);
}

// Round 7
// 25.299 us; speedup vs baseline: 1.4957x; 1.4957x over previous
//
#include <hip/hip_runtime.h>
#include <math.h>

#define BLOCK 256
#define EPB 64        // elements per block in stage/conv kernel
#define TAPS 16
#define HALO (TAPS - 1)

__device__ __forceinline__ float eluf(float v) { return v > 0.0f ? v : expm1f(v); }
__device__ __forceinline__ float dot4(float4 a, float4 b) {
    return a.x * b.x + a.y * b.y + a.z * b.z + a.w * b.w;
}

// Kernel 1: coalesced stage -> LDS (xor-swizzled) -> conv1+conv2 -> s[b] (float2)
// 4 threads per element: thread (e, j) computes conv1 output h_j (w1 is a shared
// 16-tap filter for all 4 outputs), then 4-lane shfl reduce forms (sr, si).
__global__ __launch_bounds__(BLOCK, 4) void NF_conv_kernel(
    const float* __restrict__ x,
    const float* __restrict__ w1, const float* __restrict__ b1,
    const float* __restrict__ w2, const float* __restrict__ b2,
    float2* __restrict__ s, int B)
{
    __shared__ float4 xs[EPB * 32];   // 32 KiB

    const int t = threadIdx.x;
    const int b0 = blockIdx.x * EPB;
    const float4* xf4 = reinterpret_cast<const float4*>(x);
    const float4* w1v = reinterpret_cast<const float4*>(w1);

    // ---- stage: 8 perfectly-coalesced f4 loads per thread (1 KB/wave/instr) ----
    float4 tmp[8];
    const long gbase = (long)b0 * 32;
    const bool full = (b0 + EPB) <= B;
    if (full) {
#pragma unroll
        for (int k = 0; k < 8; ++k)
            tmp[k] = xf4[gbase + k * 256 + t];
    } else {
#pragma unroll
        for (int k = 0; k < 8; ++k) {
            int e = 8 * k + (t >> 5);
            tmp[k] = (b0 + e < B) ? xf4[gbase + k * 256 + t]
                                  : make_float4(0.f, 0.f, 0.f, 0.f);
        }
    }
#pragma unroll
    for (int k = 0; k < 8; ++k) {
        int e = 8 * k + (t >> 5);
        int i = t & 31;
        xs[e * 32 + (i ^ (e & 7))] = tmp[k];
    }
    __syncthreads();

    // ---- conv1 (thread (e,j) -> h_j) + conv2 via 4-lane reduce ----
    const int e = t >> 2;
    const int j = t & 3;
    float acc = b1[0];
#pragma unroll
    for (int c = 0; c < 2; ++c)
#pragma unroll
        for (int p = 0; p < 4; ++p)
            acc += dot4(xs[e * 32 + ((c * 16 + j * 4 + p) ^ (e & 7))], w1v[c * 4 + p]);
    float h = eluf(acc);

    float pr = h * w2[j];
    float pi = h * w2[4 + j];
    pr += __shfl_xor(pr, 1);  pr += __shfl_xor(pr, 2);
    pi += __shfl_xor(pi, 1);  pi += __shfl_xor(pi, 2);

    if (j == 0 && (b0 + e) < B) {
        float sr = eluf(pr + b2[0]);
        float si = eluf(pi + b2[1]);
        s[b0 + e] = make_float2(sr, si);
    }
}

// Kernel 2: 16-tap complex FIR along batch axis, s (float2) -> out (float2).
__global__ __launch_bounds__(BLOCK) void NF_fir_kernel(
    const float2* __restrict__ s,
    const float* __restrict__ tr, const float* __restrict__ ti,
    float2* __restrict__ out, int B)
{
    __shared__ float s_r[BLOCK + HALO];
    __shared__ float s_i[BLOCK + HALO];

    const int t = threadIdx.x;
    const long base = (long)blockIdx.x * BLOCK;
    const long b = base + t;

    if (t < HALO) {
        long hb = base - HALO + t;
        float2 v = (hb >= 0) ? s[hb] : make_float2(0.f, 0.f);
        s_r[t] = v.x;  s_i[t] = v.y;
    }
    {
        float2 v = (b < B) ? s[b] : make_float2(0.f, 0.f);
        s_r[HALO + t] = v.x;  s_i[HALO + t] = v.y;
    }
    __syncthreads();

    if (b < B) {
        float yr = 0.f, yi = 0.f;
#pragma unroll
        for (int jj = 0; jj < TAPS; ++jj) {
            float a = s_r[HALO + t - jj];
            float c = s_i[HALO + t - jj];
            float trj = tr[jj], tij = ti[jj];
            yr += a * trj - c * tij;
            yi += a * tij + c * trj;
        }
        out[b] = make_float2(yr, yi);
    }
}

extern "C" void kernel_launch(void* const* d_in, const int* in_sizes, int n_in,
                              void* d_out, int out_size, void* d_ws, size_t ws_size,
                              hipStream_t stream) {
    const float* x  = (const float*)d_in[0];
    const float* w1 = (const float*)d_in[1];
    const float* b1 = (const float*)d_in[2];
    const float* w2 = (const float*)d_in[3];
    const float* b2 = (const float*)d_in[4];
    const float* tr = (const float*)d_in[5];
    const float* ti = (const float*)d_in[6];
    float2* out = (float2*)d_out;

    const int B = in_sizes[0] / 128;       // x is (B, 2, 64)
    float2* s = (float2*)d_ws;             // B float2 = 1.6 MB scratch

    const int grid1 = (B + EPB - 1) / EPB;
    NF_conv_kernel<<<grid1, BLOCK, 0, stream>>>(x, w1, b1, w2, b2, s, B);

    const int grid2 = (B + BLOCK - 1) / BLOCK;
    NF_fir_kernel<<<grid2, BLOCK, 0, stream>>>(s, tr, ti, out, B);
}